// Round 1
// baseline (279.345 us; speedup 1.0000x reference)
//
#include <hip/hip_runtime.h>

// KappaGCN layer on MI355X. KAPPA=-1, N=8192, D=512.
// Pipeline:
//   conv_bf16(X) ; conv_wt(W) -> bf16 operands
//   gemm_tn: mx = X @ W (bf16 MFMA, fp32 out)
//   rowstats: per-row mobius factor, gamma, gamma-1
//   convA_rowred: A fp32 -> bf16, fused fp32 denom/alpha row-reductions
//   build_bt: B_T[d][j] = (factor*gamma)_j * mx[j][d]  (bf16, transposed)
//   gemm_tn: nom = A_bf16 @ B_T
//   epilogue: midpoint scaling + mobius_scalar_mul + exp0(relu(log0(.)))

#define NR 8192
#define DD 512

typedef unsigned int u32;
typedef unsigned short u16;
typedef __attribute__((ext_vector_type(8))) short bf16x8;
typedef __attribute__((ext_vector_type(4))) float f32x4;

__device__ __forceinline__ u16 f2bf(float f) {
  u32 u = __float_as_uint(f);
  u32 r = u + 0x7FFFu + ((u >> 16) & 1u);   // round-to-nearest-even
  return (u16)(r >> 16);
}

__device__ __forceinline__ void gload16(const void* g, void* l) {
  __builtin_amdgcn_global_load_lds(
      (const __attribute__((address_space(1))) u32*)g,
      (__attribute__((address_space(3))) u32*)l, 16, 0, 0);
}

__device__ __forceinline__ float wred(float v) {
  #pragma unroll
  for (int off = 32; off; off >>= 1) v += __shfl_xor(v, off, 64);
  return v;
}

// ---------------- converts ----------------

__global__ __launch_bounds__(256) void conv_bf16(const float* __restrict__ in,
                                                 u16* __restrict__ out) {
  const int i = (blockIdx.x * 256 + threadIdx.x) * 8;
  float4 a = *(const float4*)&in[i];
  float4 b = *(const float4*)&in[i + 4];
  u32 r[4];
  r[0] = (u32)f2bf(a.x) | ((u32)f2bf(a.y) << 16);
  r[1] = (u32)f2bf(a.z) | ((u32)f2bf(a.w) << 16);
  r[2] = (u32)f2bf(b.x) | ((u32)f2bf(b.y) << 16);
  r[3] = (u32)f2bf(b.z) | ((u32)f2bf(b.w) << 16);
  *(uint4*)(out + i) = *(const uint4*)r;
}

// W [K=512][N=512] fp32 -> Wt [N][K] bf16
__global__ __launch_bounds__(256) void conv_wt(const float* __restrict__ W,
                                               u16* __restrict__ Wt) {
  const int idx = blockIdx.x * 256 + threadIdx.x;  // 0..32767
  const int n  = idx >> 6;
  const int k0 = (idx & 63) * 8;
  u32 r[4];
  #pragma unroll
  for (int j = 0; j < 4; ++j) {
    float lo = W[(size_t)(k0 + 2*j    ) * DD + n];
    float hi = W[(size_t)(k0 + 2*j + 1) * DD + n];
    r[j] = (u32)f2bf(lo) | ((u32)f2bf(hi) << 16);
  }
  *(uint4*)(Wt + (size_t)n * DD + k0) = *(const uint4*)r;
}

// ---------------- GEMM: C[M][N] = A[M][K](bf16) * Bt[N][K](bf16), fp32 out --
// 128x128 tile, BK=32, 4 waves (2x2), per-wave 64x64 (4x4 frags of 16x16x32).
__global__ __launch_bounds__(256) void gemm_tn(const u16* __restrict__ A,
                                               const u16* __restrict__ Bt,
                                               float* __restrict__ C,
                                               int M, int N, int K) {
  constexpr int BK = 32;
  __shared__ __align__(16) u16 ldsA[2][128 * BK];
  __shared__ __align__(16) u16 ldsB[2][128 * BK];
  const int t = threadIdx.x;
  const int lane = t & 63, w = t >> 6;
  const int wm = w >> 1, wn = w & 1;
  const int m0 = blockIdx.y * 128, n0 = blockIdx.x * 128;
  const int lr = lane & 15, lk = lane >> 4;

  const int rowA = t >> 2;          // 0..63
  const int c8   = (t & 3) * 8;     // k-offset in elems
  const u16* gA = A  + (size_t)(m0 + rowA) * K + c8;
  const u16* gB = Bt + (size_t)(n0 + rowA) * K + c8;
  const size_t rstep = (size_t)64 * K;

  f32x4 acc[4][4];
  #pragma unroll
  for (int i = 0; i < 4; ++i)
    #pragma unroll
    for (int j = 0; j < 4; ++j) acc[i][j] = (f32x4){0.f, 0.f, 0.f, 0.f};

  const int nT = K / BK;

  // prologue: stage tile 0 into buf 0
  gload16(gA,         &ldsA[0][w * 512]);
  gload16(gA + rstep, &ldsA[0][2048 + w * 512]);
  gload16(gB,         &ldsB[0][w * 512]);
  gload16(gB + rstep, &ldsB[0][2048 + w * 512]);
  __syncthreads();

  for (int tt = 0; tt < nT; ++tt) {
    const int cur = tt & 1;
    if (tt + 1 < nT) {
      const int nxt = cur ^ 1;
      const int kk = (tt + 1) * BK;
      gload16(gA + kk,         &ldsA[nxt][w * 512]);
      gload16(gA + kk + rstep, &ldsA[nxt][2048 + w * 512]);
      gload16(gB + kk,         &ldsB[nxt][w * 512]);
      gload16(gB + kk + rstep, &ldsB[nxt][2048 + w * 512]);
    }
    bf16x8 af[4], bfv[4];
    #pragma unroll
    for (int i = 0; i < 4; ++i) {
      af[i]  = *(const bf16x8*)&ldsA[cur][(wm * 64 + i * 16 + lr) * BK + lk * 8];
      bfv[i] = *(const bf16x8*)&ldsB[cur][(wn * 64 + i * 16 + lr) * BK + lk * 8];
    }
    #pragma unroll
    for (int mi = 0; mi < 4; ++mi)
      #pragma unroll
      for (int ni = 0; ni < 4; ++ni)
        acc[mi][ni] = __builtin_amdgcn_mfma_f32_16x16x32_bf16(
            af[mi], bfv[ni], acc[mi][ni], 0, 0, 0);
    __syncthreads();
  }

  // C/D layout: col = lane&15, row = (lane>>4)*4 + reg   [m89-verified]
  float* Cw = C + (size_t)(m0 + wm * 64 + lk * 4) * N + n0 + wn * 64 + lr;
  #pragma unroll
  for (int mi = 0; mi < 4; ++mi)
    #pragma unroll
    for (int ni = 0; ni < 4; ++ni)
      #pragma unroll
      for (int v = 0; v < 4; ++v)
        Cw[(size_t)(mi * 16 + v) * N + ni * 16] = acc[mi][ni][v];
}

// ---------------- row stats (mobius_matvec scalars + gamma) ----------------
// one wave per row; lane covers 8 of 512 elems
__global__ __launch_bounds__(256) void rowstats(const float* __restrict__ X,
                                                const float* __restrict__ mx,
                                                float* __restrict__ fg,
                                                float* __restrict__ g1) {
  const int row  = (blockIdx.x << 2) + (threadIdx.x >> 6);
  const int lane = threadIdx.x & 63;
  const float* xr = X  + (size_t)row * DD + lane * 8;
  const float* mr = mx + (size_t)row * DD + lane * 8;
  float4 a0 = *(const float4*)xr, a1 = *(const float4*)(xr + 4);
  float4 b0 = *(const float4*)mr, b1 = *(const float4*)(mr + 4);
  float sx = a0.x*a0.x + a0.y*a0.y + a0.z*a0.z + a0.w*a0.w
           + a1.x*a1.x + a1.y*a1.y + a1.z*a1.z + a1.w*a1.w;
  float sm = b0.x*b0.x + b0.y*b0.y + b0.z*b0.z + b0.w*b0.w
           + b1.x*b1.x + b1.y*b1.y + b1.z*b1.z + b1.w*b1.w;
  sx = wred(sx); sm = wred(sm);
  if (lane == 0) {
    float xn  = sqrtf(fmaxf(sx, 1e-20f));
    float mxn = sqrtf(fmaxf(sm, 1e-20f));
    float at  = atanhf(fminf(xn, 0.9999999f));
    float t_  = tanhf(mxn / xn * at);
    bool  z   = (mxn <= 1e-10f);
    float factor = z ? 0.f : t_ / mxn;
    float xwsq   = z ? 0.f : t_ * t_ * (sm / (mxn * mxn));
    float g = 2.f / (1.f - xwsq);          // kappa = -1
    g = fmaxf(g, 1e-15f);
    fg[row] = factor * g;
    g1[row] = g - 1.f;
  }
}

// ---------------- A fp32->bf16 + fused fp32 row reductions ----------------
__global__ __launch_bounds__(256) void convA_rowred(const float* __restrict__ A,
                                                    const float* __restrict__ g1,
                                                    u16* __restrict__ Abf,
                                                    float* __restrict__ den,
                                                    float* __restrict__ al) {
  const int row = blockIdx.x;
  const int t = threadIdx.x;
  const int lane = t & 63, w = t >> 6;
  const float* ar = A + (size_t)row * NR;
  u32* orow = (u32*)(Abf + (size_t)row * NR);
  float s = 0.f, sg = 0.f;
  #pragma unroll
  for (int it = 0; it < 8; ++it) {
    const int base = it * 1024 + t * 4;
    float4 v = *(const float4*)&ar[base];
    float4 g = *(const float4*)&g1[base];
    u32 p0 = (u32)f2bf(v.x) | ((u32)f2bf(v.y) << 16);
    u32 p1 = (u32)f2bf(v.z) | ((u32)f2bf(v.w) << 16);
    uint2 pk; pk.x = p0; pk.y = p1;
    *(uint2*)&orow[base >> 1] = pk;
    s  += (v.x + v.y) + (v.z + v.w);
    sg += v.x * g.x + v.y * g.y + v.z * g.z + v.w * g.w;
  }
  s = wred(s); sg = wred(sg);
  __shared__ float red[8];
  if (lane == 0) { red[w] = s; red[4 + w] = sg; }
  __syncthreads();
  if (t == 0) {
    al[row]  = red[0] + red[1] + red[2] + red[3];
    den[row] = red[4] + red[5] + red[6] + red[7];
  }
}

// ---------------- B_T build: Bt[d][j] = fg[j] * mx[j][d] (bf16) -----------
__global__ __launch_bounds__(256) void build_bt(const float* __restrict__ mx,
                                                const float* __restrict__ fg,
                                                u16* __restrict__ Bt) {
  __shared__ float tile[64][65];
  const int j0 = blockIdx.x * 64, d0 = blockIdx.y * 64;
  const int t = threadIdx.x;
  const int r0 = t >> 4, c4 = (t & 15) * 4;
  #pragma unroll
  for (int p = 0; p < 4; ++p) {
    const int r = r0 + p * 16;
    const float s = fg[j0 + r];
    float4 v = *(const float4*)&mx[(size_t)(j0 + r) * DD + d0 + c4];
    tile[r][c4 + 0] = s * v.x; tile[r][c4 + 1] = s * v.y;
    tile[r][c4 + 2] = s * v.z; tile[r][c4 + 3] = s * v.w;
  }
  __syncthreads();
  const int dr = t >> 2, jc = (t & 3) * 16;
  u32 r[8];
  #pragma unroll
  for (int u = 0; u < 8; ++u) {
    float lo = tile[jc + 2 * u][dr];
    float hi = tile[jc + 2 * u + 1][dr];
    r[u] = (u32)f2bf(lo) | ((u32)f2bf(hi) << 16);
  }
  u32* dst = (u32*)(Bt + (size_t)(d0 + dr) * NR + j0 + jc);
  *(uint4*)dst       = *(const uint4*)&r[0];
  *((uint4*)dst + 1) = *(const uint4*)&r[4];
}

// ---------------- epilogue ----------------
// one wave per row: midpoint scale, mobius_scalar_mul(alpha,.), exp0(relu(log0))
__global__ __launch_bounds__(256) void epilogue(const float* __restrict__ nom,
                                                const float* __restrict__ den_,
                                                const float* __restrict__ al_,
                                                float* __restrict__ out) {
  const int row  = (blockIdx.x << 2) + (threadIdx.x >> 6);
  const int lane = threadIdx.x & 63;
  const float* nr = nom + (size_t)row * DD + lane * 8;
  float de = den_[row];
  de = (de >= 0.f ? 1.f : -1.f) * fmaxf(fabsf(de), 1e-10f);
  const float alpha = al_[row];
  float4 n0 = *(const float4*)nr, n1 = *(const float4*)(nr + 4);
  float v[8] = {n0.x / de, n0.y / de, n0.z / de, n0.w / de,
                n1.x / de, n1.y / de, n1.z / de, n1.w / de};
  float sq = 0.f;
  #pragma unroll
  for (int j = 0; j < 8; ++j) sq += v[j] * v[j];
  sq = wred(sq);
  float s1 = 1.f + sqrtf(fmaxf(1.f - sq, 1e-10f));     // 1+sqrt(max(1+k*sq,EPS))
  float an = sqrtf(fmaxf(sq / (s1 * s1), 1e-20f));     // ||a_mean|| clamped
  float t2 = tanhf(alpha * atanhf(fminf(an, 0.9999999f)));
  float f2 = t2 / (an * s1);                           // res = f2 * v
  float xsq = f2 * f2 * sq;
  float xn = sqrtf(fmaxf(xsq, 1e-20f));
  float lf = atanhf(fminf(xn, 0.9999999f)) / xn;       // logmap0 scale
  float u[8]; float us = 0.f;
  #pragma unroll
  for (int j = 0; j < 8; ++j) {
    u[j] = fmaxf(lf * f2 * v[j], 0.f);                 // relu(log0)
    us += u[j] * u[j];
  }
  us = wred(us);
  float un = sqrtf(fmaxf(us, 1e-20f));
  float ef = tanhf(un) / un;                           // expmap0 scale
  float o[8];
  #pragma unroll
  for (int j = 0; j < 8; ++j) o[j] = ef * u[j];
  float* orow = out + (size_t)row * DD + lane * 8;
  *(float4*)orow       = (float4){o[0], o[1], o[2], o[3]};
  *(float4*)(orow + 4) = (float4){o[4], o[5], o[6], o[7]};
}

// ---------------- launch ----------------
extern "C" void kernel_launch(void* const* d_in, const int* in_sizes, int n_in,
                              void* d_out, int out_size, void* d_ws, size_t ws_size,
                              hipStream_t stream) {
  const float* X = (const float*)d_in[0];
  const float* A = (const float*)d_in[1];
  const float* W = (const float*)d_in[2];
  float* out = (float*)d_out;
  char* ws = (char*)d_ws;

  u16*   Abf = (u16*)(ws);                          // 134217728 B
  float* mx  = (float*)(ws + 134217728);            // 16777216 B (reused as nom)
  u16*   Xbf = (u16*)(ws + 150994944);              // 8388608 B (reused as Bt)
  u16*   Wt  = (u16*)(ws + 159383552);              // 524288 B
  float* fg  = (float*)(ws + 159907840);            // 32768 B
  float* g1  = (float*)(ws + 159940608);            // 32768 B
  float* den = (float*)(ws + 159973376);            // 32768 B
  float* al  = (float*)(ws + 160006144);            // 32768 B

  conv_bf16<<<2048, 256, 0, stream>>>(X, Xbf);                       // X -> bf16
  conv_wt<<<128, 256, 0, stream>>>(W, Wt);                           // W^T -> bf16
  gemm_tn<<<dim3(4, 64), 256, 0, stream>>>(Xbf, Wt, mx, NR, DD, DD); // mx = X@W
  rowstats<<<2048, 256, 0, stream>>>(X, mx, fg, g1);
  convA_rowred<<<NR, 256, 0, stream>>>(A, g1, Abf, den, al);
  u16* Bt = Xbf;
  build_bt<<<dim3(128, 8), 256, 0, stream>>>(mx, fg, Bt);
  float* nom = mx;
  gemm_tn<<<dim3(4, 64), 256, 0, stream>>>(Abf, Bt, nom, NR, DD, NR); // nom = A@Bt^T
  epilogue<<<2048, 256, 0, stream>>>(nom, den, al, out);
}

// Round 2
// 236.112 us; speedup vs baseline: 1.1831x; 1.1831x over previous
//
#include <hip/hip_runtime.h>

// KappaGCN layer on MI355X. KAPPA=-1, N=8192, D=512.
// Round 2: split-K=4 on the big GEMM (occupancy 1 -> 4 blocks/CU),
// sibling-XCD block mapping, epilogue sums split-K partials.

#define NR 8192
#define DD 512

typedef unsigned int u32;
typedef unsigned short u16;
typedef __attribute__((ext_vector_type(8))) short bf16x8;
typedef __attribute__((ext_vector_type(4))) float f32x4;

__device__ __forceinline__ u16 f2bf(float f) {
  u32 u = __float_as_uint(f);
  u32 r = u + 0x7FFFu + ((u >> 16) & 1u);   // round-to-nearest-even
  return (u16)(r >> 16);
}

__device__ __forceinline__ void gload16(const void* g, void* l) {
  __builtin_amdgcn_global_load_lds(
      (const __attribute__((address_space(1))) u32*)g,
      (__attribute__((address_space(3))) u32*)l, 16, 0, 0);
}

__device__ __forceinline__ float wred(float v) {
  #pragma unroll
  for (int off = 32; off; off >>= 1) v += __shfl_xor(v, off, 64);
  return v;
}

// ---------------- converts ----------------

__global__ __launch_bounds__(256) void conv_bf16(const float* __restrict__ in,
                                                 u16* __restrict__ out) {
  const int i = (blockIdx.x * 256 + threadIdx.x) * 8;
  float4 a = *(const float4*)&in[i];
  float4 b = *(const float4*)&in[i + 4];
  u32 r[4];
  r[0] = (u32)f2bf(a.x) | ((u32)f2bf(a.y) << 16);
  r[1] = (u32)f2bf(a.z) | ((u32)f2bf(a.w) << 16);
  r[2] = (u32)f2bf(b.x) | ((u32)f2bf(b.y) << 16);
  r[3] = (u32)f2bf(b.z) | ((u32)f2bf(b.w) << 16);
  *(uint4*)(out + i) = *(const uint4*)r;
}

// W [K=512][N=512] fp32 -> Wt [N][K] bf16
__global__ __launch_bounds__(256) void conv_wt(const float* __restrict__ W,
                                               u16* __restrict__ Wt) {
  const int idx = blockIdx.x * 256 + threadIdx.x;  // 0..32767
  const int n  = idx >> 6;
  const int k0 = (idx & 63) * 8;
  u32 r[4];
  #pragma unroll
  for (int j = 0; j < 4; ++j) {
    float lo = W[(size_t)(k0 + 2*j    ) * DD + n];
    float hi = W[(size_t)(k0 + 2*j + 1) * DD + n];
    r[j] = (u32)f2bf(lo) | ((u32)f2bf(hi) << 16);
  }
  *(uint4*)(Wt + (size_t)n * DD + k0) = *(const uint4*)r;
}

// ---------------- GEMM: C[M][N] = A[M][K](bf16) * Bt[N][K](bf16), fp32 out --
// 128x128 tile, BK=32, 4 waves (2x2), per-wave 64x64 (4x4 frags of 16x16x32).
// Split-K: grid = ntm * 4 * nsplit blocks; sibling-XCD mapping puts the 4
// nt-siblings (which share the same A panel) 8 apart in blockIdx so the
// default %8 XCD round-robin co-locates them on one XCD's L2.
__global__ __launch_bounds__(256) void gemm_tn_sk(const u16* __restrict__ A,
                                                  const u16* __restrict__ Bt,
                                                  float* __restrict__ C0,
                                                  float* __restrict__ Cext,
                                                  int M, int N, int K,
                                                  int kchunk, int ntm) {
  constexpr int BK = 32;
  __shared__ __align__(16) u16 ldsA[2][128 * BK];
  __shared__ __align__(16) u16 ldsB[2][128 * BK];
  // decode block -> (mt, nt, kc); grid is a multiple of 32
  const int p  = blockIdx.x;
  const int q  = (p >> 5) * 8 + (p & 7);
  const int nt = (p >> 3) & 3;
  const int mt = q % ntm;
  const int kc = q / ntm;

  const int t = threadIdx.x;
  const int lane = t & 63, w = t >> 6;
  const int wm = w >> 1, wn = w & 1;
  const int m0 = mt * 128, n0 = nt * 128;
  const int kbeg = kc * kchunk;
  const int lr = lane & 15, lk = lane >> 4;

  const int rowA = t >> 2;          // 0..63
  const int c8   = (t & 3) * 8;     // k-offset in elems
  const u16* gA = A  + (size_t)(m0 + rowA) * K + kbeg + c8;
  const u16* gB = Bt + (size_t)(n0 + rowA) * K + kbeg + c8;
  const size_t rstep = (size_t)64 * K;

  f32x4 acc[4][4];
  #pragma unroll
  for (int i = 0; i < 4; ++i)
    #pragma unroll
    for (int j = 0; j < 4; ++j) acc[i][j] = (f32x4){0.f, 0.f, 0.f, 0.f};

  const int nT = kchunk / BK;

  gload16(gA,         &ldsA[0][w * 512]);
  gload16(gA + rstep, &ldsA[0][2048 + w * 512]);
  gload16(gB,         &ldsB[0][w * 512]);
  gload16(gB + rstep, &ldsB[0][2048 + w * 512]);
  __syncthreads();

  for (int tt = 0; tt < nT; ++tt) {
    const int cur = tt & 1;
    if (tt + 1 < nT) {
      const int nxt = cur ^ 1;
      const int kk = (tt + 1) * BK;
      gload16(gA + kk,         &ldsA[nxt][w * 512]);
      gload16(gA + kk + rstep, &ldsA[nxt][2048 + w * 512]);
      gload16(gB + kk,         &ldsB[nxt][w * 512]);
      gload16(gB + kk + rstep, &ldsB[nxt][2048 + w * 512]);
    }
    bf16x8 af[4], bfv[4];
    #pragma unroll
    for (int i = 0; i < 4; ++i) {
      af[i]  = *(const bf16x8*)&ldsA[cur][(wm * 64 + i * 16 + lr) * BK + lk * 8];
      bfv[i] = *(const bf16x8*)&ldsB[cur][(wn * 64 + i * 16 + lr) * BK + lk * 8];
    }
    #pragma unroll
    for (int mi = 0; mi < 4; ++mi)
      #pragma unroll
      for (int ni = 0; ni < 4; ++ni)
        acc[mi][ni] = __builtin_amdgcn_mfma_f32_16x16x32_bf16(
            af[mi], bfv[ni], acc[mi][ni], 0, 0, 0);
    __syncthreads();
  }

  float* C = (kc == 0) ? C0 : (Cext + (size_t)(kc - 1) * M * N);
  // C/D layout: col = lane&15, row = (lane>>4)*4 + reg   [m89-verified]
  float* Cw = C + (size_t)(m0 + wm * 64 + lk * 4) * N + n0 + wn * 64 + lr;
  #pragma unroll
  for (int mi = 0; mi < 4; ++mi)
    #pragma unroll
    for (int ni = 0; ni < 4; ++ni)
      #pragma unroll
      for (int v = 0; v < 4; ++v)
        Cw[(size_t)(mi * 16 + v) * N + ni * 16] = acc[mi][ni][v];
}

// ---------------- row stats (mobius_matvec scalars + gamma) ----------------
__global__ __launch_bounds__(256) void rowstats(const float* __restrict__ X,
                                                const float* __restrict__ mx,
                                                float* __restrict__ fg,
                                                float* __restrict__ g1) {
  const int row  = (blockIdx.x << 2) + (threadIdx.x >> 6);
  const int lane = threadIdx.x & 63;
  const float* xr = X  + (size_t)row * DD + lane * 8;
  const float* mr = mx + (size_t)row * DD + lane * 8;
  float4 a0 = *(const float4*)xr, a1 = *(const float4*)(xr + 4);
  float4 b0 = *(const float4*)mr, b1 = *(const float4*)(mr + 4);
  float sx = a0.x*a0.x + a0.y*a0.y + a0.z*a0.z + a0.w*a0.w
           + a1.x*a1.x + a1.y*a1.y + a1.z*a1.z + a1.w*a1.w;
  float sm = b0.x*b0.x + b0.y*b0.y + b0.z*b0.z + b0.w*b0.w
           + b1.x*b1.x + b1.y*b1.y + b1.z*b1.z + b1.w*b1.w;
  sx = wred(sx); sm = wred(sm);
  if (lane == 0) {
    float xn  = sqrtf(fmaxf(sx, 1e-20f));
    float mxn = sqrtf(fmaxf(sm, 1e-20f));
    float at  = atanhf(fminf(xn, 0.9999999f));
    float t_  = tanhf(mxn / xn * at);
    bool  z   = (mxn <= 1e-10f);
    float factor = z ? 0.f : t_ / mxn;
    float xwsq   = z ? 0.f : t_ * t_ * (sm / (mxn * mxn));
    float g = 2.f / (1.f - xwsq);          // kappa = -1
    g = fmaxf(g, 1e-15f);
    fg[row] = factor * g;
    g1[row] = g - 1.f;
  }
}

// ---------------- A fp32->bf16 + fused fp32 row reductions ----------------
__global__ __launch_bounds__(256) void convA_rowred(const float* __restrict__ A,
                                                    const float* __restrict__ g1,
                                                    u16* __restrict__ Abf,
                                                    float* __restrict__ den,
                                                    float* __restrict__ al) {
  const int row = blockIdx.x;
  const int t = threadIdx.x;
  const int lane = t & 63, w = t >> 6;
  const float* ar = A + (size_t)row * NR;
  u32* orow = (u32*)(Abf + (size_t)row * NR);
  float s = 0.f, sg = 0.f;
  #pragma unroll
  for (int it = 0; it < 8; ++it) {
    const int base = it * 1024 + t * 4;
    float4 v = *(const float4*)&ar[base];
    float4 g = *(const float4*)&g1[base];
    u32 p0 = (u32)f2bf(v.x) | ((u32)f2bf(v.y) << 16);
    u32 p1 = (u32)f2bf(v.z) | ((u32)f2bf(v.w) << 16);
    uint2 pk; pk.x = p0; pk.y = p1;
    *(uint2*)&orow[base >> 1] = pk;
    s  += (v.x + v.y) + (v.z + v.w);
    sg += v.x * g.x + v.y * g.y + v.z * g.z + v.w * g.w;
  }
  s = wred(s); sg = wred(sg);
  __shared__ float red[8];
  if (lane == 0) { red[w] = s; red[4 + w] = sg; }
  __syncthreads();
  if (t == 0) {
    al[row]  = red[0] + red[1] + red[2] + red[3];
    den[row] = red[4] + red[5] + red[6] + red[7];
  }
}

// ---------------- B_T build: Bt[d][j] = fg[j] * mx[j][d] (bf16) -----------
__global__ __launch_bounds__(256) void build_bt(const float* __restrict__ mx,
                                                const float* __restrict__ fg,
                                                u16* __restrict__ Bt) {
  __shared__ float tile[64][65];
  const int j0 = blockIdx.x * 64, d0 = blockIdx.y * 64;
  const int t = threadIdx.x;
  const int r0 = t >> 4, c4 = (t & 15) * 4;
  #pragma unroll
  for (int p = 0; p < 4; ++p) {
    const int r = r0 + p * 16;
    const float s = fg[j0 + r];
    float4 v = *(const float4*)&mx[(size_t)(j0 + r) * DD + d0 + c4];
    tile[r][c4 + 0] = s * v.x; tile[r][c4 + 1] = s * v.y;
    tile[r][c4 + 2] = s * v.z; tile[r][c4 + 3] = s * v.w;
  }
  __syncthreads();
  const int dr = t >> 2, jc = (t & 3) * 16;
  u32 r[8];
  #pragma unroll
  for (int u = 0; u < 8; ++u) {
    float lo = tile[jc + 2 * u][dr];
    float hi = tile[jc + 2 * u + 1][dr];
    r[u] = (u32)f2bf(lo) | ((u32)f2bf(hi) << 16);
  }
  u32* dst = (u32*)(Bt + (size_t)(d0 + dr) * NR + j0 + jc);
  *(uint4*)dst       = *(const uint4*)&r[0];
  *((uint4*)dst + 1) = *(const uint4*)&r[4];
}

// ---------------- epilogue (sums split-K partials) ----------------
__global__ __launch_bounds__(256) void epilogue(const float* __restrict__ P0,
                                                const float* __restrict__ P1,
                                                const float* __restrict__ P2,
                                                const float* __restrict__ P3,
                                                const float* __restrict__ den_,
                                                const float* __restrict__ al_,
                                                float* __restrict__ out,
                                                int nsplit) {
  const int row  = (blockIdx.x << 2) + (threadIdx.x >> 6);
  const int lane = threadIdx.x & 63;
  const size_t ro = (size_t)row * DD + lane * 8;
  float4 n0 = *(const float4*)(P0 + ro), n1 = *(const float4*)(P0 + ro + 4);
  if (nsplit > 1) {
    float4 a = *(const float4*)(P1 + ro), b = *(const float4*)(P1 + ro + 4);
    n0.x += a.x; n0.y += a.y; n0.z += a.z; n0.w += a.w;
    n1.x += b.x; n1.y += b.y; n1.z += b.z; n1.w += b.w;
  }
  if (nsplit > 2) {
    float4 a = *(const float4*)(P2 + ro), b = *(const float4*)(P2 + ro + 4);
    n0.x += a.x; n0.y += a.y; n0.z += a.z; n0.w += a.w;
    n1.x += b.x; n1.y += b.y; n1.z += b.z; n1.w += b.w;
    a = *(const float4*)(P3 + ro); b = *(const float4*)(P3 + ro + 4);
    n0.x += a.x; n0.y += a.y; n0.z += a.z; n0.w += a.w;
    n1.x += b.x; n1.y += b.y; n1.z += b.z; n1.w += b.w;
  }
  float de = den_[row];
  de = (de >= 0.f ? 1.f : -1.f) * fmaxf(fabsf(de), 1e-10f);
  const float alpha = al_[row];
  float v[8] = {n0.x / de, n0.y / de, n0.z / de, n0.w / de,
                n1.x / de, n1.y / de, n1.z / de, n1.w / de};
  float sq = 0.f;
  #pragma unroll
  for (int j = 0; j < 8; ++j) sq += v[j] * v[j];
  sq = wred(sq);
  float s1 = 1.f + sqrtf(fmaxf(1.f - sq, 1e-10f));     // 1+sqrt(max(1+k*sq,EPS))
  float an = sqrtf(fmaxf(sq / (s1 * s1), 1e-20f));     // ||a_mean|| clamped
  float t2 = tanhf(alpha * atanhf(fminf(an, 0.9999999f)));
  float f2 = t2 / (an * s1);                           // res = f2 * v
  float xsq = f2 * f2 * sq;
  float xn = sqrtf(fmaxf(xsq, 1e-20f));
  float lf = atanhf(fminf(xn, 0.9999999f)) / xn;       // logmap0 scale
  float u[8]; float us = 0.f;
  #pragma unroll
  for (int j = 0; j < 8; ++j) {
    u[j] = fmaxf(lf * f2 * v[j], 0.f);                 // relu(log0)
    us += u[j] * u[j];
  }
  us = wred(us);
  float un = sqrtf(fmaxf(us, 1e-20f));
  float ef = tanhf(un) / un;                           // expmap0 scale
  float o[8];
  #pragma unroll
  for (int j = 0; j < 8; ++j) o[j] = ef * u[j];
  float* orow = out + (size_t)row * DD + lane * 8;
  *(float4*)orow       = (float4){o[0], o[1], o[2], o[3]};
  *(float4*)(orow + 4) = (float4){o[4], o[5], o[6], o[7]};
}

// ---------------- launch ----------------
extern "C" void kernel_launch(void* const* d_in, const int* in_sizes, int n_in,
                              void* d_out, int out_size, void* d_ws, size_t ws_size,
                              hipStream_t stream) {
  const float* X = (const float*)d_in[0];
  const float* A = (const float*)d_in[1];
  const float* W = (const float*)d_in[2];
  float* out = (float*)d_out;
  char* ws = (char*)d_ws;

  u16*   Abf = (u16*)(ws);                          // 134217728 B
  float* mx  = (float*)(ws + 134217728);            // 16777216 B (= split-K P0)
  u16*   Xbf = (u16*)(ws + 150994944);              // 8388608 B (reused as Bt)
  u16*   Wt  = (u16*)(ws + 159383552);              // 524288 B
  float* fg  = (float*)(ws + 159907840);            // 32768 B
  float* g1  = (float*)(ws + 159940608);            // 32768 B
  float* den = (float*)(ws + 159973376);            // 32768 B
  float* al  = (float*)(ws + 160006144);            // 32768 B
  float* Pext = (float*)(ws + 160038912);           // up to 3 x 16777216 B

  const size_t MN = (size_t)NR * DD * 4;            // bytes per partial
  int nsplit = 1;
  if (ws_size >= 160038912 + 3 * MN) nsplit = 4;
  else if (ws_size >= 160038912 + 1 * MN) nsplit = 2;

  conv_bf16<<<2048, 256, 0, stream>>>(X, Xbf);
  conv_wt<<<128, 256, 0, stream>>>(W, Wt);
  // mx = X @ W  (no split; grid 256, sibling map is a bijection for any ntm)
  gemm_tn_sk<<<256, 256, 0, stream>>>(Xbf, Wt, mx, mx, NR, DD, DD, DD, 64);
  rowstats<<<2048, 256, 0, stream>>>(X, mx, fg, g1);
  convA_rowred<<<NR, 256, 0, stream>>>(A, g1, Abf, den, al);
  u16* Bt = Xbf;
  build_bt<<<dim3(128, 8), 256, 0, stream>>>(mx, fg, Bt);
  // nom = A @ Bt^T with split-K; P0 overlays mx (dead after build_bt)
  float* nom0 = mx;
  gemm_tn_sk<<<256 * nsplit, 256, 0, stream>>>(Abf, Bt, nom0, Pext,
                                               NR, DD, NR, NR / nsplit, 64);
  epilogue<<<2048, 256, 0, stream>>>(nom0, Pext, Pext + (MN >> 2),
                                     Pext + (MN >> 1), den, al, out, nsplit);
}